// Round 12
// baseline (30.384 us; speedup 1.0000x reference)
//
#include <hip/hip_runtime.h>
#include <math.h>

#define QN  4
#define CN  256
#define BN  32
#define NN  4096
#define WV  4            // waves per block
#define RPW 32           // rows per wave
#define TR  4            // rows per tile
#define NT  8            // tiles per wave (RPW/TR)
#define SPB 32           // blocks per batch (NN/(WV*VW... = NN/(WV*RPW))

// ---------------------------------------------------------------------------
// Fused single-pass (no-max softmax: |s| bounded ~16, fp32 headroom huge).
// DENSE variant: loads are UNCONDITIONAL (hypothesis: random 1KB-hole reads
// are DRAM-activate-bound, so skipping masked rows saves no time; dense is
// perfectly striped).  Masking is applied arithmetically: p = 0 for masked
// rows.  Main loop otherwise identical to validated round-8 kernel: lane
// owns channels 4*lane..+3 for score AND pool (no LDS in main loop); per
// 4-row tile: 16 dot partials, reduce-scatter butterfly (17 shuffles),
// 1 exp on holder lane, readlane-broadcast pool.  NT=8 static -> the loop
// fully unrolls, registers rename, compiler emits counted vmcnt waits.
// grid = BN*SPB = 1024 blocks x 256 thr; ~100 VGPR, 16 KB LDS -> 4 wv/SIMD.
// ---------------------------------------------------------------------------
__global__ __launch_bounds__(256) void k_fused(
    const float* __restrict__ h, const int* __restrict__ mask,
    const float* __restrict__ qr,
    float* __restrict__ P, float* __restrict__ Lp)
{
    __shared__ float s_part[WV][QN * CN];   // 16 KB, epilogue only
    __shared__ float s_lp[WV][QN];

    const int b    = blockIdx.x >> 5;
    const int sub  = blockIdx.x & (SPB - 1);
    const int w    = threadIdx.x >> 6;
    const int lane = threadIdx.x & 63;

    const int n0    = (sub * WV + w) * RPW;
    const size_t gn = (size_t)b * NN + n0;
    const float* __restrict__ hb = h + gn * CN + lane * 4;

    // lane's 4 channels of each query (scale folded in): 16 VGPRs
    float4 q4[QN];
#pragma unroll
    for (int q = 0; q < QN; ++q) {
        float4 tq = *(const float4*)(qr + q * CN + lane * 4);
        tq.x *= 0.0625f; tq.y *= 0.0625f; tq.z *= 0.0625f; tq.w *= 0.0625f;
        q4[q] = tq;
    }

    // mask bits for this wave's 32 rows (one ballot, SGPR-resident)
    const unsigned long long mbits =
        __ballot(lane < RPW ? (mask[gn + lane] != 0) : true);

    float4 acc[QN];
#pragma unroll
    for (int q = 0; q < QN; ++q) acc[q] = make_float4(0.f, 0.f, 0.f, 0.f);

    float lheld = 0.f;                   // p-sum for this lane's held (r,q)
    const int rheld = (lane >> 2) & 3;   // row-in-tile whose sum lane holds

    float4 vc[TR], vn[TR];

    // prologue: tile 0, unconditional dense load
#pragma unroll
    for (int j = 0; j < TR; ++j)
        vc[j] = *(const float4*)(hb + (size_t)j * CN);

#pragma unroll
    for (int t = 0; t < NT; ++t) {
        // ---- prefetch tile t+1 (unconditional, perfectly striped) ----
        if (t + 1 < NT) {
#pragma unroll
            for (int j = 0; j < TR; ++j)
                vn[j] = *(const float4*)(hb + (size_t)((t + 1) * TR + j) * CN);
        }

        // ---- dot partials: cur[r*4+q] over lane's 4 channels ----
        float cur[16];
#pragma unroll
        for (int r = 0; r < TR; ++r)
#pragma unroll
            for (int q = 0; q < QN; ++q)
                cur[r * 4 + q] = vc[r].x * q4[q].x + vc[r].y * q4[q].y
                               + vc[r].z * q4[q].z + vc[r].w * q4[q].w;

        // ---- reduce-scatter butterfly: value v lands on (lane&15)==v ----
#pragma unroll
        for (int k = 0; k < 4; ++k) {
            const int  nv = 8 >> k;
            const bool bk = (lane >> k) & 1;
#pragma unroll
            for (int j = 0; j < nv; ++j) {
                const float snd = bk ? cur[2 * j] : cur[2 * j + 1];
                const float rcv = __shfl_xor(snd, 1 << k, 64);
                cur[j] = (bk ? cur[2 * j + 1] : cur[2 * j]) + rcv;
            }
        }
        float sv = cur[0];                       // partial over 16-lane group
        sv += __shfl_xor(sv, 16, 64);
        sv += __shfl_xor(sv, 32, 64);            // full 64-lane sum

        // ---- exp on holder lane; masked row -> 0 ----
        const bool  mk = ((mbits >> (t * TR + rheld)) & 1ull) != 0;
        const float pv = mk ? 0.f : __expf(sv);
        lheld += pv;

        // ---- pool: p via readlane (SGPR) * lane's channels ----
#pragma unroll
        for (int r = 0; r < TR; ++r)
#pragma unroll
            for (int q = 0; q < QN; ++q) {
                const float prq = __uint_as_float(
                    __builtin_amdgcn_readlane(__float_as_uint(pv), r * 4 + q));
                acc[q].x += prq * vc[r].x;
                acc[q].y += prq * vc[r].y;
                acc[q].z += prq * vc[r].z;
                acc[q].w += prq * vc[r].w;
            }

        // rotate pipeline (renamed away by full unroll)
#pragma unroll
        for (int j = 0; j < TR; ++j) vc[j] = vn[j];
    }

    // ---- l[q]: fold slots (lane bits 2,3); lanes 0..3 hold q=lane ----
    float lt = lheld;
    lt += __shfl_xor(lt, 4, 64);
    lt += __shfl_xor(lt, 8, 64);

    // ---- block combine via LDS; write per-block partial ----
#pragma unroll
    for (int q = 0; q < QN; ++q)
        *(float4*)&s_part[w][q * CN + lane * 4] = acc[q];
    if (lane < QN) s_lp[w][lane] = lt;
    __syncthreads();
    {
        const int tt = threadIdx.x;              // 256 threads x float4
        float4 o = make_float4(0.f, 0.f, 0.f, 0.f);
#pragma unroll
        for (int ww = 0; ww < WV; ++ww) {
            const float4 v = *(const float4*)&s_part[ww][tt * 4];
            o.x += v.x; o.y += v.y; o.z += v.z; o.w += v.w;
        }
        ((float4*)(P + (size_t)blockIdx.x * (QN * CN)))[tt] = o;
        if (tt < QN)
            Lp[blockIdx.x * QN + tt] =
                s_lp[0][tt] + s_lp[1][tt] + s_lp[2][tt] + s_lp[3][tt];
    }
}

// ---------------------------------------------------------------------------
// Combine SPB block-partials per batch and divide by l (0 if l==0).
// FULL unroll -> all 32 partial loads in flight (one latency round-trip).
// grid = BN*QN blocks x 256 threads; q block-uniform (scalar L loads).
// ---------------------------------------------------------------------------
__global__ __launch_bounds__(256) void k_div(
    const float* __restrict__ P, const float* __restrict__ Lp,
    float* __restrict__ out)
{
    const int b   = blockIdx.x >> 2;
    const int q   = blockIdx.x & 3;
    const int idx = q * CN + threadIdx.x;

    float o = 0.f, l = 0.f;
#pragma unroll
    for (int s = 0; s < SPB; ++s) {
        o += P[(size_t)(b * SPB + s) * (QN * CN) + idx];
        l += Lp[(b * SPB + s) * QN + q];
    }
    out[(size_t)b * (QN * CN) + idx] = (l > 0.f) ? o / l : 0.f;
}

extern "C" void kernel_launch(void* const* d_in, const int* in_sizes, int n_in,
                              void* d_out, int out_size, void* d_ws, size_t ws_size,
                              hipStream_t stream) {
    const float* h    = (const float*)d_in[0];
    const int*   mask = (const int*)d_in[1];
    const float* qr   = (const float*)d_in[2];
    float*       out  = (float*)d_out;

    float* P  = (float*)d_ws;                           // [1024][Q*C] = 4 MB
    float* Lp = P + (size_t)BN * SPB * QN * CN;         // [1024][Q]   = 16 KB

    k_fused<<<BN * SPB, 256, 0, stream>>>(h, mask, qr, P, Lp);
    k_div  <<<BN * QN, 256, 0, stream>>>(P, Lp, out);
}